// Round 7
// baseline (202.575 us; speedup 1.0000x reference)
//
#include <hip/hip_runtime.h>
#include <stdint.h>
#include <math.h>

typedef __attribute__((ext_vector_type(8))) __bf16 bf16x8;
typedef __attribute__((ext_vector_type(4))) float f32x4;

template <int V> struct ic { static constexpr int value = V; };

// ---- fp32 -> bf16 (RNE) ----
__device__ __forceinline__ unsigned short f2bf(float f) {
    unsigned u = __float_as_uint(f);
    u += 0x7FFF + ((u >> 16) & 1);
    return (unsigned short)(u >> 16);
}

__global__ __launch_bounds__(256)
void f32_to_bf16_k(const float* __restrict__ in, unsigned short* __restrict__ out, int n4) {
    int i = blockIdx.x * blockDim.x + threadIdx.x;
    int stride = gridDim.x * blockDim.x;
    for (; i < n4; i += stride) {
        float4 v = reinterpret_cast<const float4*>(in)[i];
        ushort4 o;
        o.x = f2bf(v.x); o.y = f2bf(v.y); o.z = f2bf(v.z); o.w = f2bf(v.w);
        reinterpret_cast<ushort4*>(out)[i] = o;
    }
}

__global__ __launch_bounds__(256)
void w_convert_k(const float* __restrict__ Wq, const float* __restrict__ Wk,
                 const float* __restrict__ Wv, unsigned short* __restrict__ out, int n4) {
    const float* src = blockIdx.y == 0 ? Wq : (blockIdx.y == 1 ? Wk : Wv);
    unsigned short* dst = out + (size_t)blockIdx.y * n4 * 4;
    int i = blockIdx.x * blockDim.x + threadIdx.x;
    int stride = gridDim.x * blockDim.x;
    for (; i < n4; i += stride) {
        float4 v = reinterpret_cast<const float4*>(src)[i];
        ushort4 o;
        o.x = f2bf(v.x); o.y = f2bf(v.y); o.z = f2bf(v.z); o.w = f2bf(v.w);
        reinterpret_cast<ushort4*>(dst)[i] = o;
    }
}

__device__ __forceinline__ void gload16(const unsigned short* g, unsigned short* l) {
    __builtin_amdgcn_global_load_lds(
        (const __attribute__((address_space(1))) unsigned int*)g,
        (__attribute__((address_space(3))) unsigned int*)l, 16, 0, 0);
}

// ================== 256x256 8-phase NT GEMM (m201-style schedule) ==================
// C[m,n] = scale * sum_k A[m,k]*B[n,k];  A:[M,K], B:[N,K] row-major bf16.
// 512 thr = 8 waves: wm=wid>>2 (2 M-stripes of 64), wn=wid&3 (4 N-stripes of 32).
// Wave frag rows: A row = mh*128 + wm*64 + mm*16 + rsel  (mh=M-half, mm=0..3)
//                 B row = nh*128 + wn*32 + nn*16 + rsel  (nh=N-half, nn=0..1)
// -> each phase's quadrant (mh,nh) touches exactly A-half{mh}, B-half{nh}.
// LDS: As/Bs[2][256*64] bf16 = 128 KiB total; chunk cc of row stored at (cc^(row&7))
// via pre-swizzled global source (dest linear for global_load_lds), same XOR on ds_read.
// Per iter (2 K-tiles: buf0=2i, buf1=2i+1), 8 phases; stage stream for pair i+1:
//   p1:b0.Ah0 p2:b0.Bh0 p3:b0.Bh1 p4:b0.Ah1 p5:b1.Ah0 p6:b1.Bh0 p7:b1.Bh1 p0(next):b1.Ah1
// (each target's last reader is >=1 barrier before the stage issue).
// vmcnt(6) at p3/p7 only: guarantees all halves staged >=4 phases ago landed before use.
template <typename CT, bool TRIE, bool KLIM>
__global__ __launch_bounds__(512, 2)
void gemm256(const unsigned short* __restrict__ A, const unsigned short* __restrict__ B,
             CT* __restrict__ C, int lda, int ldb, int ldc, int K,
             long long sA, long long sB, long long sC, float scale)
{
    // bijective XCD-aware remap (m204)
    const int nbx = gridDim.x;
    const int nwg = nbx * gridDim.y;
    const int orig = blockIdx.y * nbx + blockIdx.x;
    const int q8 = nwg >> 3, r8 = nwg & 7;
    const int xcd = orig & 7, idx = orig >> 3;
    const int work = (xcd < r8 ? xcd * (q8 + 1) : r8 * (q8 + 1) + (xcd - r8) * q8) + idx;

    int br, bc;
    if constexpr (TRIE) {
        int rr = (int)((sqrtf(8.0f * (float)work + 1.0f) - 1.0f) * 0.5f);
        while ((rr + 1) * (rr + 2) / 2 <= work) ++rr;
        while (rr * (rr + 1) / 2 > work) --rr;
        br = rr; bc = work - rr * (rr + 1) / 2;
    } else {
        br = work / nbx; bc = work % nbx;
    }

    A += (long long)blockIdx.z * sA;
    B += (long long)blockIdx.z * sB;
    C += (long long)blockIdx.z * sC;

    int kmax = K;
    if (KLIM) { int kl = (br + 1) * 256; kmax = kl < K ? kl : K; }

    __shared__ unsigned short As[2][256 * 64];
    __shared__ unsigned short Bs[2][256 * 64];

    const int t    = threadIdx.x;
    const int lane = t & 63;
    const int wid  = t >> 6;
    const int wm   = wid >> 2;        // 0..1
    const int wn   = wid & 3;         // 0..3
    const int m0   = br * 256, n0 = bc * 256;
    const int rsel = lane & 15;
    const int gsel = lane >> 4;       // 0..3

    f32x4 acc[8][4];
#pragma unroll
    for (int m = 0; m < 8; ++m)
#pragma unroll
        for (int n = 0; n < 4; ++n) acc[m][n] = (f32x4){0.f, 0.f, 0.f, 0.f};

    // stage one 128-row half of A/B for K-tile kt into buffer buf
    auto stageA = [&](int buf, int h, int kt) {
#pragma unroll
        for (int i = 0; i < 2; ++i) {
            int ci = i * 512 + t;                // 0..1023
            int row = ci >> 3, cc = ci & 7;
            gload16(A + (long long)(m0 + h * 128 + row) * lda + kt * 64 + ((cc ^ (row & 7)) * 8),
                    &As[buf][h * 8192 + ci * 8]);
        }
    };
    auto stageB = [&](int buf, int h, int kt) {
#pragma unroll
        for (int i = 0; i < 2; ++i) {
            int ci = i * 512 + t;
            int row = ci >> 3, cc = ci & 7;
            gload16(B + (long long)(n0 + h * 128 + row) * ldb + kt * 64 + ((cc ^ (row & 7)) * 8),
                    &Bs[buf][h * 8192 + ci * 8]);
        }
    };

    auto readA = [&](int buf, int mh, bf16x8 (&dst)[4][2]) {
#pragma unroll
        for (int mm = 0; mm < 4; ++mm)
#pragma unroll
            for (int ks = 0; ks < 2; ++ks) {
                int r  = mh * 128 + wm * 64 + mm * 16 + rsel;
                int cc = ks * 4 + gsel;
                dst[mm][ks] = *reinterpret_cast<const bf16x8*>(
                    &As[buf][r * 64 + ((cc ^ (r & 7)) * 8)]);
            }
    };
    auto readB = [&](int buf, int nh, bf16x8 (&dst)[2][2]) {
#pragma unroll
        for (int nn = 0; nn < 2; ++nn)
#pragma unroll
            for (int ks = 0; ks < 2; ++ks) {
                int rb = nh * 128 + wn * 32 + nn * 16 + rsel;
                int cc = ks * 4 + gsel;
                dst[nn][ks] = *reinterpret_cast<const bf16x8*>(
                    &Bs[buf][rb * 64 + ((cc ^ (rb & 7)) * 8)]);
            }
    };

    auto mfma16 = [&](auto MH, auto NH, bf16x8 (&aF)[4][2], bf16x8 (&bF)[2][2]) {
        constexpr int mh = decltype(MH)::value, nh = decltype(NH)::value;
        __builtin_amdgcn_s_setprio(1);
#pragma unroll
        for (int mm = 0; mm < 4; ++mm)
#pragma unroll
            for (int nn = 0; nn < 2; ++nn)
#pragma unroll
                for (int ks = 0; ks < 2; ++ks)
                    acc[mh * 4 + mm][nh * 2 + nn] = __builtin_amdgcn_mfma_f32_16x16x32_bf16(
                        aF[mm][ks], bF[nn][ks], acc[mh * 4 + mm][nh * 2 + nn], 0, 0, 0);
        __builtin_amdgcn_s_setprio(0);
    };

#define BARF()  do { __builtin_amdgcn_s_barrier(); __builtin_amdgcn_sched_barrier(0); } while (0)
#define LGKM0() do { asm volatile("s_waitcnt lgkmcnt(0)" ::: "memory"); \
                     __builtin_amdgcn_sched_barrier(0); } while (0)

    const int nk  = kmax >> 6;
    const int nkk = nk >> 1;            // iterations (2 K-tiles each); always >= 2 here

    // prologue: pair 0 -> tiles 0,1 fully staged
    stageA(0, 0, 0); stageB(0, 0, 0); stageB(0, 1, 0); stageA(0, 1, 0);
    stageA(1, 0, 1); stageB(1, 0, 1); stageB(1, 1, 1); stageA(1, 1, 1);
    asm volatile("s_waitcnt vmcnt(0)" ::: "memory");
    BARF();

    bf16x8 aF[4][2], bF0[2][2], bF1[2][2];

    for (int i = 0; i < nkk; ++i) {
        const bool pf = (i + 1 < nkk);
        const int t2 = 2 * i + 2, t3 = 2 * i + 3;
        // ---- phase 0 : quadrant (0,0) of tile 2i ----
        if (i) stageA(1, 1, 2 * i + 1);           // pair i, s7: buf1.Ah1
        readA(0, 0, aF); readB(0, 0, bF0);
        __builtin_amdgcn_s_barrier();
        LGKM0();
        mfma16(ic<0>{}, ic<0>{}, aF, bF0);
        BARF();
        // ---- phase 1 : (0,1) ----
        if (pf) stageA(0, 0, t2);
        readB(0, 1, bF1);
        __builtin_amdgcn_s_barrier();
        LGKM0();
        mfma16(ic<0>{}, ic<1>{}, aF, bF1);
        BARF();
        // ---- phase 2 : (1,1) ----
        if (pf) stageB(0, 0, t2);
        readA(0, 1, aF);
        __builtin_amdgcn_s_barrier();
        LGKM0();
        mfma16(ic<1>{}, ic<1>{}, aF, bF1);
        BARF();
        // ---- phase 3 : (1,0) ; counted vmcnt ----
        if (pf) {
            stageB(0, 1, t2);
            asm volatile("s_waitcnt vmcnt(6)" ::: "memory");
        } else {
            asm volatile("s_waitcnt vmcnt(0)" ::: "memory");
        }
        __builtin_amdgcn_s_barrier();
        __builtin_amdgcn_sched_barrier(0);
        mfma16(ic<1>{}, ic<0>{}, aF, bF0);
        BARF();
        // ---- phase 4 : quadrant (0,0) of tile 2i+1 ----
        if (pf) stageA(0, 1, t2);
        readA(1, 0, aF); readB(1, 0, bF0);
        __builtin_amdgcn_s_barrier();
        LGKM0();
        mfma16(ic<0>{}, ic<0>{}, aF, bF0);
        BARF();
        // ---- phase 5 : (0,1) ----
        if (pf) stageA(1, 0, t3);
        readB(1, 1, bF1);
        __builtin_amdgcn_s_barrier();
        LGKM0();
        mfma16(ic<0>{}, ic<1>{}, aF, bF1);
        BARF();
        // ---- phase 6 : (1,1) ----
        if (pf) stageB(1, 0, t3);
        readA(1, 1, aF);
        __builtin_amdgcn_s_barrier();
        LGKM0();
        mfma16(ic<1>{}, ic<1>{}, aF, bF1);
        BARF();
        // ---- phase 7 : (1,0) ; counted vmcnt ----
        if (pf) {
            stageB(1, 1, t3);
            asm volatile("s_waitcnt vmcnt(6)" ::: "memory");
        }
        __builtin_amdgcn_s_barrier();
        __builtin_amdgcn_sched_barrier(0);
        mfma16(ic<1>{}, ic<0>{}, aF, bF0);
        BARF();
    }
#undef BARF
#undef LGKM0

    // epilogue: D[row][col], col = lane&15, row = (lane>>4)*4 + i  (m89-verified)
    const int rowl = gsel * 4;
#pragma unroll
    for (int mh = 0; mh < 2; ++mh)
#pragma unroll
    for (int mm = 0; mm < 4; ++mm)
#pragma unroll
    for (int nh = 0; nh < 2; ++nh)
#pragma unroll
    for (int nn = 0; nn < 2; ++nn)
#pragma unroll
    for (int i2 = 0; i2 < 4; ++i2) {
        int r  = m0 + mh * 128 + wm * 64 + mm * 16 + rowl + i2;
        int cI = n0 + nh * 128 + wn * 32 + nn * 16 + rsel;
        float v = acc[mh * 4 + mm][nh * 2 + nn][i2] * scale;
        if constexpr (sizeof(CT) == 2)
            ((unsigned short*)C)[(long long)r * ldc + cI] = f2bf(v);
        else
            ((float*)C)[(long long)r * ldc + cI] = v;
    }
}

// ---- causal row softmax: 1 global read (LDS-cached), vectorized ----
__device__ __forceinline__ float waveMax(float v) {
#pragma unroll
    for (int o = 32; o > 0; o >>= 1) v = fmaxf(v, __shfl_xor(v, o, 64));
    return v;
}
__device__ __forceinline__ float waveSum(float v) {
#pragma unroll
    for (int o = 32; o > 0; o >>= 1) v += __shfl_xor(v, o, 64);
    return v;
}

__global__ __launch_bounds__(256)
void softmax_causal(const float* __restrict__ S, unsigned short* __restrict__ P, int Slen) {
    __shared__ float e[2048];
    __shared__ float red[4];
    long long row = blockIdx.x;                 // b*Slen + q
    int q = (int)(row % Slen);
    const float* srow = S + row * (long long)Slen;
    unsigned short* prow = P + row * (long long)Slen;
    int len = q + 1;
    int t = threadIdx.x;

    int nfull = len >> 2;
    float mx = -3.0e38f;
    for (int i = t; i < nfull; i += 256) {
        float4 v = reinterpret_cast<const float4*>(srow)[i];
        e[4 * i + 0] = v.x; e[4 * i + 1] = v.y;
        e[4 * i + 2] = v.z; e[4 * i + 3] = v.w;
        mx = fmaxf(fmaxf(fmaxf(mx, v.x), v.y), fmaxf(v.z, v.w));
    }
    if (t < (len & 3)) {
        float v = srow[nfull * 4 + t];
        e[nfull * 4 + t] = v;
        mx = fmaxf(mx, v);
    }
    mx = waveMax(mx);
    if ((t & 63) == 0) red[t >> 6] = mx;
    __syncthreads();
    mx = fmaxf(fmaxf(red[0], red[1]), fmaxf(red[2], red[3]));

    float sum = 0.f;
    for (int k = t; k < len; k += 256) {
        float v = __expf(e[k] - mx);
        e[k] = v;
        sum += v;
    }
    sum = waveSum(sum);
    __syncthreads();
    if ((t & 63) == 0) red[t >> 6] = sum;
    __syncthreads();
    sum = red[0] + red[1] + red[2] + red[3];
    float inv = 1.0f / sum;

    int wlim = ((q >> 8) + 1) << 8;             // PV (BM=256) reads k < roundup(len,256)
    __syncthreads();                            // e[] writes visible
    for (int i = t; i < (wlim >> 2); i += 256) {
        int k = 4 * i;
        ushort4 o;
        o.x = (k + 0 < len) ? f2bf(e[k + 0] * inv) : (unsigned short)0;
        o.y = (k + 1 < len) ? f2bf(e[k + 1] * inv) : (unsigned short)0;
        o.z = (k + 2 < len) ? f2bf(e[k + 2] * inv) : (unsigned short)0;
        o.w = (k + 3 < len) ? f2bf(e[k + 3] * inv) : (unsigned short)0;
        reinterpret_cast<ushort4*>(prow)[i] = o;
    }
}

extern "C" void kernel_launch(void* const* d_in, const int* in_sizes, int n_in,
                              void* d_out, int out_size, void* d_ws, size_t ws_size,
                              hipStream_t stream) {
    const int B = 4, S = 2048, D = 1024;
    const float* X  = (const float*)d_in[0];
    const float* Wq = (const float*)d_in[1];
    const float* Wk = (const float*)d_in[2];
    const float* Wv = (const float*)d_in[3];
    float* out = (float*)d_out;

    char* ws = (char*)d_ws;
    unsigned short* Xb  = (unsigned short*)ws; ws += (size_t)B * S * D * 2;
    unsigned short* Wqb = (unsigned short*)ws; ws += (size_t)D * D * 2;  // Wq,Wk,Wv contiguous
    unsigned short* Wkb = (unsigned short*)ws; ws += (size_t)D * D * 2;
    unsigned short* Wvb = (unsigned short*)ws; ws += (size_t)D * D * 2;
    unsigned short* Qb  = (unsigned short*)ws; ws += (size_t)B * S * D * 2;  // Q,K contiguous
    unsigned short* Kb  = (unsigned short*)ws; ws += (size_t)B * S * D * 2;
    unsigned short* Vt  = (unsigned short*)ws; ws += (size_t)B * S * D * 2;  // [b][e][k]
    float*          Sc  = (float*)ws;          ws += (size_t)B * S * S * 4;
    unsigned short* P   = (unsigned short*)ws; ws += (size_t)B * S * S * 2;

    f32_to_bf16_k<<<2048, 256, 0, stream>>>(X, Xb, B * S * D / 4);
    w_convert_k<<<dim3(512, 3), 256, 0, stream>>>(Wq, Wk, Wv, Wqb, D * D / 4);

    dim3 blk(512);
    // Q and K in one dispatch: grid (4, 32, 2) = 256 blocks
    gemm256<unsigned short, false, false>
        <<<dim3(D / 256, B * S / 256, 2), blk, 0, stream>>>(
        Xb, Wqb, Qb, D, D, D, D, 0, (long long)D * D, (long long)B * S * D, 1.0f);

    // Vt[b] = Wv @ Xb[b]^T : grid (8, 4, 4) = 128 blocks
    gemm256<unsigned short, false, false>
        <<<dim3(S / 256, D / 256, B), blk, 0, stream>>>(
        Wvb, Xb, Vt, D, D, S, D, 0, (long long)S * D, (long long)D * S, 1.0f);

    // scores = (Q K^T)/32 : triangular 256-blocks, 36/batch, fp32
    const int nbt = (S / 256) * (S / 256 + 1) / 2;   // 36
    gemm256<float, true, false>
        <<<dim3(nbt, 1, B), blk, 0, stream>>>(
        Qb, Kb, Sc, D, D, S, D, (long long)S * D, (long long)S * D, (long long)S * S, 0.03125f);

    softmax_causal<<<B * S, 256, 0, stream>>>(Sc, P, S);

    // out = P @ Vt^T : grid (4, 8, 4) = 128 blocks, KLIM (kmax = (br+1)*256)
    gemm256<float, false, true>
        <<<dim3(D / 256, S / 256, B), blk, 0, stream>>>(
        P, Vt, out, S, S, D, S, (long long)S * S, (long long)D * S, (long long)S * D, 1.0f);
}

// Round 8
// 178.876 us; speedup vs baseline: 1.1325x; 1.1325x over previous
//
#include <hip/hip_runtime.h>
#include <stdint.h>
#include <math.h>

typedef __attribute__((ext_vector_type(8))) __bf16 bf16x8;
typedef __attribute__((ext_vector_type(4))) float f32x4;

// ---- fp32 -> bf16 (RNE) ----
__device__ __forceinline__ unsigned short f2bf(float f) {
    unsigned u = __float_as_uint(f);
    u += 0x7FFF + ((u >> 16) & 1);
    return (unsigned short)(u >> 16);
}

__global__ __launch_bounds__(256)
void f32_to_bf16_k(const float* __restrict__ in, unsigned short* __restrict__ out, int n4) {
    int i = blockIdx.x * blockDim.x + threadIdx.x;
    int stride = gridDim.x * blockDim.x;
    for (; i < n4; i += stride) {
        float4 v = reinterpret_cast<const float4*>(in)[i];
        ushort4 o;
        o.x = f2bf(v.x); o.y = f2bf(v.y); o.z = f2bf(v.z); o.w = f2bf(v.w);
        reinterpret_cast<ushort4*>(out)[i] = o;
    }
}

__global__ __launch_bounds__(256)
void w_convert_k(const float* __restrict__ Wq, const float* __restrict__ Wk,
                 const float* __restrict__ Wv, unsigned short* __restrict__ out, int n4) {
    const float* src = blockIdx.y == 0 ? Wq : (blockIdx.y == 1 ? Wk : Wv);
    unsigned short* dst = out + (size_t)blockIdx.y * n4 * 4;
    int i = blockIdx.x * blockDim.x + threadIdx.x;
    int stride = gridDim.x * blockDim.x;
    for (; i < n4; i += stride) {
        float4 v = reinterpret_cast<const float4*>(src)[i];
        ushort4 o;
        o.x = f2bf(v.x); o.y = f2bf(v.y); o.z = f2bf(v.z); o.w = f2bf(v.w);
        reinterpret_cast<ushort4*>(dst)[i] = o;
    }
}

__device__ __forceinline__ void gload16(const unsigned short* g, unsigned short* l) {
    __builtin_amdgcn_global_load_lds(
        (const __attribute__((address_space(1))) unsigned int*)g,
        (__attribute__((address_space(3))) unsigned int*)l, 16, 0, 0);
}

// ============ NT GEMM core (round-6 proven): BK=64, counted-vmcnt dbuf, XOR swizzle ====
// 128x128 tile, 256 threads (4 waves 2x2), LDS 64KB -> 2 blocks/CU.
// C[m,n] = scale * sum_k A[m,k]*B[n,k];  A:[M,K], B:[N,K] row-major bf16.
// MODE 0: dense grid (br=work/nbx, bc=work%nbx), kmax=K.
// MODE 1: triangular job list; block does job `work`, plus job nwg+(work>>4) when
//         (work&15)==8 (spreads the 8 extra tiles/batch one-per-XCD-chunk).
// MODE 2: paired causal rows: jobs (br=p, kmax=(p+1)*BM) and (br=totj-1-p,
//         kmax=(totj-p)*BM) -> uniform 34 K-steps per block.
template <typename CT, int MODE>
__global__ __launch_bounds__(256, 2)
void gemm8(const unsigned short* __restrict__ A, const unsigned short* __restrict__ B,
           CT* __restrict__ C, int lda, int ldb, int ldc, int K,
           long long sA, long long sB, long long sC, float scale, int totj)
{
    constexpr int BM = 128, BN = 128;
    constexpr int FM = 4, FN = 4;
    constexpr int ACH = BM * 8;                  // A 16B-chunks per tile
    constexpr int LPT = (BM + BN) * 8 / 256;     // 8 loads/thread/tile

    // bijective XCD-aware work remap (m204), per z-slice
    const int nbx = gridDim.x;
    const int nwg = nbx * gridDim.y;
    const int orig = blockIdx.y * nbx + blockIdx.x;
    const int q8 = nwg >> 3, r8 = nwg & 7;
    const int xcd = orig & 7, idx = orig >> 3;
    const int work = (xcd < r8 ? xcd * (q8 + 1) : r8 * (q8 + 1) + (xcd - r8) * q8) + idx;

    A += (long long)blockIdx.z * sA;
    B += (long long)blockIdx.z * sB;
    C += (long long)blockIdx.z * sC;

    __shared__ unsigned short As[2][BM * 64];
    __shared__ unsigned short Bs[2][BN * 64];

    const int t    = threadIdx.x;
    const int lane = t & 63;
    const int wid  = t >> 6;
    const int wm   = wid >> 1, wn = wid & 1;
    const int rsel = lane & 15;
    const int gsel = lane >> 4;                  // 0..3

    auto stage = [&](int buf, int kt, int m0, int n0) {
        const int k0 = kt * 64;
#pragma unroll
        for (int i = 0; i < LPT; ++i) {
            int ci = i * 256 + t;
            if (ci < ACH) {
                int row = ci >> 3, cc = ci & 7;
                gload16(A + (long long)(m0 + row) * lda + k0 + ((cc ^ (row & 7)) * 8),
                        &As[buf][ci * 8]);
            } else {
                int cj = ci - ACH;
                int row = cj >> 3, cc = cj & 7;
                gload16(B + (long long)(n0 + row) * ldb + k0 + ((cc ^ (row & 7)) * 8),
                        &Bs[buf][cj * 8]);
            }
        }
    };

    auto run_tile = [&](int br, int bc, int kmax, bool first) {
        const int m0 = br * BM, n0 = bc * BN;
        f32x4 acc[FM][FN];
#pragma unroll
        for (int m = 0; m < FM; ++m)
#pragma unroll
            for (int n = 0; n < FN; ++n) acc[m][n] = (f32x4){0.f, 0.f, 0.f, 0.f};

        const int nk = kmax >> 6;
        if (!first) {                            // protect LDS from previous job's readers
            __builtin_amdgcn_s_barrier();
            __builtin_amdgcn_sched_barrier(0);
        }
        stage(0, 0, m0, n0);

        for (int kt = 0; kt < nk; ++kt) {
            const int c = kt & 1;
            __builtin_amdgcn_s_barrier();        // prev compute done -> overwrite c^1 ok
            __builtin_amdgcn_sched_barrier(0);
            if (kt + 1 < nk) {
                stage(c ^ 1, kt + 1, m0, n0);    // tile t+1 loads stay in flight
                asm volatile("s_waitcnt vmcnt(8)" ::: "memory");  // tile t fully landed
            } else {
                asm volatile("s_waitcnt vmcnt(0)" ::: "memory");
            }
            __builtin_amdgcn_s_barrier();        // collective guarantee for buf c
            __builtin_amdgcn_sched_barrier(0);

            bf16x8 aF[FM][2], bF[FN][2];
#pragma unroll
            for (int m = 0; m < FM; ++m)
#pragma unroll
                for (int ks = 0; ks < 2; ++ks) {
                    int r  = wm * (FM * 16) + m * 16 + rsel;
                    int cc = ks * 4 + gsel;
                    aF[m][ks] = *reinterpret_cast<const bf16x8*>(
                        &As[c][r * 64 + ((cc ^ (r & 7)) * 8)]);
                }
#pragma unroll
            for (int n = 0; n < FN; ++n)
#pragma unroll
                for (int ks = 0; ks < 2; ++ks) {
                    int rb = wn * (FN * 16) + n * 16 + rsel;
                    int cc = ks * 4 + gsel;
                    bF[n][ks] = *reinterpret_cast<const bf16x8*>(
                        &Bs[c][rb * 64 + ((cc ^ (rb & 7)) * 8)]);
                }

            __builtin_amdgcn_s_setprio(1);
#pragma unroll
            for (int m = 0; m < FM; ++m)
#pragma unroll
                for (int n = 0; n < FN; ++n)
#pragma unroll
                    for (int ks = 0; ks < 2; ++ks)
                        acc[m][n] = __builtin_amdgcn_mfma_f32_16x16x32_bf16(
                            aF[m][ks], bF[n][ks], acc[m][n], 0, 0, 0);
            __builtin_amdgcn_s_setprio(0);
        }

        // epilogue: D[row][col], col = lane&15, row = (lane>>4)*4 + i  (m89-verified)
        const int rowl = gsel * 4;
#pragma unroll
        for (int m = 0; m < FM; ++m) {
#pragma unroll
            for (int n = 0; n < FN; ++n) {
#pragma unroll
                for (int i = 0; i < 4; ++i) {
                    int r  = m0 + wm * (FM * 16) + m * 16 + rowl + i;
                    int cI = n0 + wn * (FN * 16) + n * 16 + rsel;
                    float v = acc[m][n][i] * scale;
                    if constexpr (sizeof(CT) == 2)
                        ((unsigned short*)C)[(long long)r * ldc + cI] = f2bf(v);
                    else
                        ((float*)C)[(long long)r * ldc + cI] = v;
                }
            }
        }
    };

    auto tri = [&](int w, int& br, int& bc) {
        int rr = (int)((sqrtf(8.0f * (float)w + 1.0f) - 1.0f) * 0.5f);
        while ((rr + 1) * (rr + 2) / 2 <= w) ++rr;
        while (rr * (rr + 1) / 2 > w) --rr;
        br = rr; bc = w - rr * (rr + 1) / 2;
    };

    if constexpr (MODE == 0) {
        run_tile(work / nbx, work % nbx, K, true);
    } else if constexpr (MODE == 1) {
        int br, bc;
        tri(work, br, bc);
        run_tile(br, bc, K, true);
        const int e = work >> 4;
        if ((work & 15) == 8 && nwg + e < totj) {
            tri(nwg + e, br, bc);
            run_tile(br, bc, K, false);
        }
    } else {
        const int p = work / nbx, bc = work % nbx;
        run_tile(p, bc, (p + 1) * BM, true);
        run_tile(totj - 1 - p, bc, (totj - p) * BM, false);
    }
}

// ---- causal row softmax: 1 global read (LDS-cached), vectorized ----
__device__ __forceinline__ float waveMax(float v) {
#pragma unroll
    for (int o = 32; o > 0; o >>= 1) v = fmaxf(v, __shfl_xor(v, o, 64));
    return v;
}
__device__ __forceinline__ float waveSum(float v) {
#pragma unroll
    for (int o = 32; o > 0; o >>= 1) v += __shfl_xor(v, o, 64);
    return v;
}

__global__ __launch_bounds__(256)
void softmax_causal(const float* __restrict__ S, unsigned short* __restrict__ P, int Slen) {
    __shared__ float e[2048];
    __shared__ float red[4];
    long long row = blockIdx.x;                 // b*Slen + q
    int q = (int)(row % Slen);
    const float* srow = S + row * (long long)Slen;
    unsigned short* prow = P + row * (long long)Slen;
    int len = q + 1;
    int t = threadIdx.x;

    int nfull = len >> 2;
    float mx = -3.0e38f;
    for (int i = t; i < nfull; i += 256) {
        float4 v = reinterpret_cast<const float4*>(srow)[i];
        e[4 * i + 0] = v.x; e[4 * i + 1] = v.y;
        e[4 * i + 2] = v.z; e[4 * i + 3] = v.w;
        mx = fmaxf(fmaxf(fmaxf(mx, v.x), v.y), fmaxf(v.z, v.w));
    }
    if (t < (len & 3)) {
        float v = srow[nfull * 4 + t];
        e[nfull * 4 + t] = v;
        mx = fmaxf(mx, v);
    }
    mx = waveMax(mx);
    if ((t & 63) == 0) red[t >> 6] = mx;
    __syncthreads();
    mx = fmaxf(fmaxf(red[0], red[1]), fmaxf(red[2], red[3]));

    float sum = 0.f;
    for (int k = t; k < len; k += 256) {
        float v = __expf(e[k] - mx);
        e[k] = v;
        sum += v;
    }
    sum = waveSum(sum);
    __syncthreads();
    if ((t & 63) == 0) red[t >> 6] = sum;
    __syncthreads();
    sum = red[0] + red[1] + red[2] + red[3];
    float inv = 1.0f / sum;

    int wlim = ((q >> 7) + 1) << 7;             // PV (BM=128) reads only k < roundup(len,128)
    __syncthreads();                            // e[] writes visible
    for (int i = t; i < (wlim >> 2); i += 256) {
        int k = 4 * i;
        ushort4 o;
        o.x = (k + 0 < len) ? f2bf(e[k + 0] * inv) : (unsigned short)0;
        o.y = (k + 1 < len) ? f2bf(e[k + 1] * inv) : (unsigned short)0;
        o.z = (k + 2 < len) ? f2bf(e[k + 2] * inv) : (unsigned short)0;
        o.w = (k + 3 < len) ? f2bf(e[k + 3] * inv) : (unsigned short)0;
        reinterpret_cast<ushort4*>(prow)[i] = o;
    }
}

extern "C" void kernel_launch(void* const* d_in, const int* in_sizes, int n_in,
                              void* d_out, int out_size, void* d_ws, size_t ws_size,
                              hipStream_t stream) {
    const int B = 4, S = 2048, D = 1024;
    const float* X  = (const float*)d_in[0];
    const float* Wq = (const float*)d_in[1];
    const float* Wk = (const float*)d_in[2];
    const float* Wv = (const float*)d_in[3];
    float* out = (float*)d_out;

    char* ws = (char*)d_ws;
    unsigned short* Xb  = (unsigned short*)ws; ws += (size_t)B * S * D * 2;
    unsigned short* Wqb = (unsigned short*)ws; ws += (size_t)D * D * 2;  // Wq,Wk,Wv contiguous
    unsigned short* Wkb = (unsigned short*)ws; ws += (size_t)D * D * 2;
    unsigned short* Wvb = (unsigned short*)ws; ws += (size_t)D * D * 2;
    unsigned short* Qb  = (unsigned short*)ws; ws += (size_t)B * S * D * 2;  // Q,K contiguous
    unsigned short* Kb  = (unsigned short*)ws; ws += (size_t)B * S * D * 2;
    unsigned short* Vt  = (unsigned short*)ws; ws += (size_t)B * S * D * 2;  // [b][e][k]
    float*          Sc  = (float*)ws;          ws += (size_t)B * S * S * 4;
    unsigned short* P   = (unsigned short*)ws; ws += (size_t)B * S * S * 2;

    f32_to_bf16_k<<<2048, 256, 0, stream>>>(X, Xb, B * S * D / 4);
    w_convert_k<<<dim3(512, 3), 256, 0, stream>>>(Wq, Wk, Wv, Wqb, D * D / 4);

    dim3 blk(256);
    // Q and K in one dispatch: grid (8, 64, 2) = 1024 blocks, MODE 0
    gemm8<unsigned short, 0><<<dim3(D / 128, B * S / 128, 2), blk, 0, stream>>>(
        Xb, Wqb, Qb, D, D, D, D, 0, (long long)D * D, (long long)B * S * D, 1.0f, 0);

    // Vt[b] = Wv @ Xb[b]^T : grid (16, 8, 4) = 512 blocks, MODE 0
    gemm8<unsigned short, 0><<<dim3(S / 128, D / 128, B), blk, 0, stream>>>(
        Wvb, Xb, Vt, D, D, S, D, 0, (long long)S * D, (long long)D * S, 1.0f, 0);

    // scores = (Q K^T)/32 : 136 tri-tiles/batch over 128 blocks/batch (8 spread extras)
    gemm8<float, 1><<<dim3(8, 16, B), blk, 0, stream>>>(
        Qb, Kb, Sc, D, D, S, D, (long long)S * D, (long long)S * D, (long long)S * S,
        0.03125f, 136);

    softmax_causal<<<B * S, 256, 0, stream>>>(Sc, P, S);

    // out = P @ Vt^T : paired rows (p, 15-p), grid (8, 8, 4) = 256 uniform blocks
    gemm8<float, 2><<<dim3(D / 128, 8, B), blk, 0, stream>>>(
        P, Vt, out, S, S, D, S, (long long)S * S, (long long)D * S, (long long)S * D,
        1.0f, 16);
}

// Round 9
// 176.087 us; speedup vs baseline: 1.1504x; 1.0158x over previous
//
#include <hip/hip_runtime.h>
#include <stdint.h>
#include <math.h>

typedef __attribute__((ext_vector_type(8))) __bf16 bf16x8;
typedef __attribute__((ext_vector_type(4))) float f32x4;

// ---- fp32 -> bf16 (RNE) ----
__device__ __forceinline__ unsigned short f2bf(float f) {
    unsigned u = __float_as_uint(f);
    u += 0x7FFF + ((u >> 16) & 1);
    return (unsigned short)(u >> 16);
}

__global__ __launch_bounds__(256)
void f32_to_bf16_k(const float* __restrict__ in, unsigned short* __restrict__ out, int n4) {
    int i = blockIdx.x * blockDim.x + threadIdx.x;
    int stride = gridDim.x * blockDim.x;
    for (; i < n4; i += stride) {
        float4 v = reinterpret_cast<const float4*>(in)[i];
        ushort4 o;
        o.x = f2bf(v.x); o.y = f2bf(v.y); o.z = f2bf(v.z); o.w = f2bf(v.w);
        reinterpret_cast<ushort4*>(out)[i] = o;
    }
}

__global__ __launch_bounds__(256)
void w_convert_k(const float* __restrict__ Wq, const float* __restrict__ Wk,
                 const float* __restrict__ Wv, unsigned short* __restrict__ out, int n4) {
    const float* src = blockIdx.y == 0 ? Wq : (blockIdx.y == 1 ? Wk : Wv);
    unsigned short* dst = out + (size_t)blockIdx.y * n4 * 4;
    int i = blockIdx.x * blockDim.x + threadIdx.x;
    int stride = gridDim.x * blockDim.x;
    for (; i < n4; i += stride) {
        float4 v = reinterpret_cast<const float4*>(src)[i];
        ushort4 o;
        o.x = f2bf(v.x); o.y = f2bf(v.y); o.z = f2bf(v.z); o.w = f2bf(v.w);
        reinterpret_cast<ushort4*>(dst)[i] = o;
    }
}

__device__ __forceinline__ void gload16(const unsigned short* g, unsigned short* l) {
    __builtin_amdgcn_global_load_lds(
        (const __attribute__((address_space(1))) unsigned int*)g,
        (__attribute__((address_space(3))) unsigned int*)l, 16, 0, 0);
}

// ============ NT GEMM core: BK=64, counted-vmcnt dbuf, XOR swizzle, hoisted ptrs ======
// 128x128 tile, 256 threads (4 waves 2x2), LDS 64KB -> 2 blocks/CU.
// C[m,n] = scale * sum_k A[m,k]*B[n,k];  A:[M,K], B:[N,K] row-major bf16.
// Staging addresses strength-reduced: 8 per-thread pointers advanced +64 elems/tile.
// MODE 0: dense grid (br=work/nbx, bc=work%nbx), kmax=K.
// MODE 1: triangular job list; block does job `work`, plus job nwg+(work>>4) when
//         (work&15)==8 (spreads extra tiles one-per-XCD-chunk, co-resident from t=0).
// MODE 3: causal-row interleave: s=work&1, pp=work>>1, col=pp&7, rp=pp>>3,
//         row = s ? 15-rp : rp, kmax=(row+1)*BM -> XCD chunks K-uniform, 2 blocks/CU.
template <typename CT, int MODE>
__global__ __launch_bounds__(256, 2)
void gemm8(const unsigned short* __restrict__ A, const unsigned short* __restrict__ B,
           CT* __restrict__ C, int lda, int ldb, int ldc, int K,
           long long sA, long long sB, long long sC, float scale, int totj)
{
    constexpr int BM = 128, BN = 128;
    constexpr int FM = 4, FN = 4;

    // bijective XCD-aware work remap (m204), per z-slice
    const int nbx = gridDim.x;
    const int nwg = nbx * gridDim.y;
    const int orig = blockIdx.y * nbx + blockIdx.x;
    const int q8 = nwg >> 3, r8 = nwg & 7;
    const int xcd = orig & 7, idx = orig >> 3;
    const int work = (xcd < r8 ? xcd * (q8 + 1) : r8 * (q8 + 1) + (xcd - r8) * q8) + idx;

    A += (long long)blockIdx.z * sA;
    B += (long long)blockIdx.z * sB;
    C += (long long)blockIdx.z * sC;

    __shared__ unsigned short As[2][BM * 64];
    __shared__ unsigned short Bs[2][BN * 64];

    const int t    = threadIdx.x;
    const int lane = t & 63;
    const int wid  = t >> 6;
    const int wm   = wid >> 1, wn = wid & 1;
    const int rsel = lane & 15;
    const int gsel = lane >> 4;                  // 0..3
    const int srow = t >> 3;                     // staging row 0..31 (chunk 0)
    const int swz  = ((t & 7) ^ (srow & 7)) * 8; // swizzled element offset (ks-invariant)

    auto run_tile = [&](int br, int bc, int kmax, bool first) {
        const int m0 = br * BM, n0 = bc * BN;
        f32x4 acc[FM][FN];
#pragma unroll
        for (int m = 0; m < FM; ++m)
#pragma unroll
            for (int n = 0; n < FN; ++n) acc[m][n] = (f32x4){0.f, 0.f, 0.f, 0.f};

        // hoisted staging pointers: 4 A-rows + 4 B-rows per thread, advance +64/tile
        const unsigned short* gpA[4];
        const unsigned short* gpB[4];
#pragma unroll
        for (int i = 0; i < 4; ++i) {
            gpA[i] = A + (long long)(m0 + srow + 32 * i) * lda + swz;
            gpB[i] = B + (long long)(n0 + srow + 32 * i) * ldb + swz;
        }

        auto stage = [&](int buf) {
#pragma unroll
            for (int i = 0; i < 4; ++i)
                gload16(gpA[i], &As[buf][i * 2048 + t * 8]);
#pragma unroll
            for (int i = 0; i < 4; ++i)
                gload16(gpB[i], &Bs[buf][i * 2048 + t * 8]);
#pragma unroll
            for (int i = 0; i < 4; ++i) { gpA[i] += 64; gpB[i] += 64; }
        };

        const int nk = kmax >> 6;
        if (!first) {                            // protect LDS from previous job's readers
            __builtin_amdgcn_s_barrier();
            __builtin_amdgcn_sched_barrier(0);
        }
        stage(0);

        for (int kt = 0; kt < nk; ++kt) {
            const int c = kt & 1;
            __builtin_amdgcn_s_barrier();        // prev compute done -> overwrite c^1 ok
            __builtin_amdgcn_sched_barrier(0);
            if (kt + 1 < nk) {
                stage(c ^ 1);                    // tile t+1 loads stay in flight
                asm volatile("s_waitcnt vmcnt(8)" ::: "memory");  // tile t fully landed
            } else {
                asm volatile("s_waitcnt vmcnt(0)" ::: "memory");
            }
            __builtin_amdgcn_s_barrier();        // collective guarantee for buf c
            __builtin_amdgcn_sched_barrier(0);

            bf16x8 aF[FM][2], bF[FN][2];
#pragma unroll
            for (int m = 0; m < FM; ++m)
#pragma unroll
                for (int ks = 0; ks < 2; ++ks) {
                    int r  = wm * (FM * 16) + m * 16 + rsel;
                    int cc = ks * 4 + gsel;
                    aF[m][ks] = *reinterpret_cast<const bf16x8*>(
                        &As[c][r * 64 + ((cc ^ (r & 7)) * 8)]);
                }
#pragma unroll
            for (int n = 0; n < FN; ++n)
#pragma unroll
                for (int ks = 0; ks < 2; ++ks) {
                    int rb = wn * (FN * 16) + n * 16 + rsel;
                    int cc = ks * 4 + gsel;
                    bF[n][ks] = *reinterpret_cast<const bf16x8*>(
                        &Bs[c][rb * 64 + ((cc ^ (rb & 7)) * 8)]);
                }

            __builtin_amdgcn_s_setprio(1);
#pragma unroll
            for (int m = 0; m < FM; ++m)
#pragma unroll
                for (int n = 0; n < FN; ++n)
#pragma unroll
                    for (int ks = 0; ks < 2; ++ks)
                        acc[m][n] = __builtin_amdgcn_mfma_f32_16x16x32_bf16(
                            aF[m][ks], bF[n][ks], acc[m][n], 0, 0, 0);
            __builtin_amdgcn_s_setprio(0);
        }

        // epilogue: D[row][col], col = lane&15, row = (lane>>4)*4 + i  (m89-verified)
        const int rowl = gsel * 4;
#pragma unroll
        for (int m = 0; m < FM; ++m) {
#pragma unroll
            for (int n = 0; n < FN; ++n) {
#pragma unroll
                for (int i = 0; i < 4; ++i) {
                    int r  = m0 + wm * (FM * 16) + m * 16 + rowl + i;
                    int cI = n0 + wn * (FN * 16) + n * 16 + rsel;
                    float v = acc[m][n][i] * scale;
                    if constexpr (sizeof(CT) == 2)
                        ((unsigned short*)C)[(long long)r * ldc + cI] = f2bf(v);
                    else
                        ((float*)C)[(long long)r * ldc + cI] = v;
                }
            }
        }
    };

    auto tri = [&](int w, int& br, int& bc) {
        int rr = (int)((sqrtf(8.0f * (float)w + 1.0f) - 1.0f) * 0.5f);
        while ((rr + 1) * (rr + 2) / 2 <= w) ++rr;
        while (rr * (rr + 1) / 2 > w) --rr;
        br = rr; bc = w - rr * (rr + 1) / 2;
    };

    if constexpr (MODE == 0) {
        run_tile(work / nbx, work % nbx, K, true);
    } else if constexpr (MODE == 1) {
        int br, bc;
        tri(work, br, bc);
        run_tile(br, bc, K, true);
        const int e = work >> 4;
        if ((work & 15) == 8 && nwg + e < totj) {
            tri(nwg + e, br, bc);
            run_tile(br, bc, K, false);
        }
    } else {
        const int s = work & 1, pp = work >> 1;
        const int col = pp & 7, rp = pp >> 3;
        const int row = s ? 15 - rp : rp;
        run_tile(row, col, (row + 1) * BM, true);
    }
}

// ---- causal row softmax: 1 global read (LDS-cached), vectorized ----
__device__ __forceinline__ float waveMax(float v) {
#pragma unroll
    for (int o = 32; o > 0; o >>= 1) v = fmaxf(v, __shfl_xor(v, o, 64));
    return v;
}
__device__ __forceinline__ float waveSum(float v) {
#pragma unroll
    for (int o = 32; o > 0; o >>= 1) v += __shfl_xor(v, o, 64);
    return v;
}

__global__ __launch_bounds__(256)
void softmax_causal(const float* __restrict__ S, unsigned short* __restrict__ P, int Slen) {
    __shared__ float e[2048];
    __shared__ float red[4];
    long long row = blockIdx.x;                 // b*Slen + q
    int q = (int)(row % Slen);
    const float* srow = S + row * (long long)Slen;
    unsigned short* prow = P + row * (long long)Slen;
    int len = q + 1;
    int t = threadIdx.x;

    int nfull = len >> 2;
    float mx = -3.0e38f;
    for (int i = t; i < nfull; i += 256) {
        float4 v = reinterpret_cast<const float4*>(srow)[i];
        e[4 * i + 0] = v.x; e[4 * i + 1] = v.y;
        e[4 * i + 2] = v.z; e[4 * i + 3] = v.w;
        mx = fmaxf(fmaxf(fmaxf(mx, v.x), v.y), fmaxf(v.z, v.w));
    }
    if (t < (len & 3)) {
        float v = srow[nfull * 4 + t];
        e[nfull * 4 + t] = v;
        mx = fmaxf(mx, v);
    }
    mx = waveMax(mx);
    if ((t & 63) == 0) red[t >> 6] = mx;
    __syncthreads();
    mx = fmaxf(fmaxf(red[0], red[1]), fmaxf(red[2], red[3]));

    float sum = 0.f;
    for (int k = t; k < len; k += 256) {
        float v = __expf(e[k] - mx);
        e[k] = v;
        sum += v;
    }
    sum = waveSum(sum);
    __syncthreads();
    if ((t & 63) == 0) red[t >> 6] = sum;
    __syncthreads();
    sum = red[0] + red[1] + red[2] + red[3];
    float inv = 1.0f / sum;

    int wlim = ((q >> 7) + 1) << 7;             // PV (BM=128) reads only k < roundup(len,128)
    __syncthreads();                            // e[] writes visible
    for (int i = t; i < (wlim >> 2); i += 256) {
        int k = 4 * i;
        ushort4 o;
        o.x = (k + 0 < len) ? f2bf(e[k + 0] * inv) : (unsigned short)0;
        o.y = (k + 1 < len) ? f2bf(e[k + 1] * inv) : (unsigned short)0;
        o.z = (k + 2 < len) ? f2bf(e[k + 2] * inv) : (unsigned short)0;
        o.w = (k + 3 < len) ? f2bf(e[k + 3] * inv) : (unsigned short)0;
        reinterpret_cast<ushort4*>(prow)[i] = o;
    }
}

extern "C" void kernel_launch(void* const* d_in, const int* in_sizes, int n_in,
                              void* d_out, int out_size, void* d_ws, size_t ws_size,
                              hipStream_t stream) {
    const int B = 4, S = 2048, D = 1024;
    const float* X  = (const float*)d_in[0];
    const float* Wq = (const float*)d_in[1];
    const float* Wk = (const float*)d_in[2];
    const float* Wv = (const float*)d_in[3];
    float* out = (float*)d_out;

    char* ws = (char*)d_ws;
    unsigned short* Xb  = (unsigned short*)ws; ws += (size_t)B * S * D * 2;
    unsigned short* Wqb = (unsigned short*)ws; ws += (size_t)D * D * 2;  // Wq,Wk,Wv contiguous
    unsigned short* Wkb = (unsigned short*)ws; ws += (size_t)D * D * 2;
    unsigned short* Wvb = (unsigned short*)ws; ws += (size_t)D * D * 2;
    unsigned short* Qb  = (unsigned short*)ws; ws += (size_t)B * S * D * 2;  // Q,K contiguous
    unsigned short* Kb  = (unsigned short*)ws; ws += (size_t)B * S * D * 2;
    unsigned short* Vt  = (unsigned short*)ws; ws += (size_t)B * S * D * 2;  // [b][e][k]
    float*          Sc  = (float*)ws;          ws += (size_t)B * S * S * 4;
    unsigned short* P   = (unsigned short*)ws; ws += (size_t)B * S * S * 2;

    f32_to_bf16_k<<<2048, 256, 0, stream>>>(X, Xb, B * S * D / 4);
    w_convert_k<<<dim3(512, 3), 256, 0, stream>>>(Wq, Wk, Wv, Wqb, D * D / 4);

    dim3 blk(256);
    // Q and K in one dispatch: grid (8, 64, 2) = 1024 blocks, MODE 0
    gemm8<unsigned short, 0><<<dim3(D / 128, B * S / 128, 2), blk, 0, stream>>>(
        Xb, Wqb, Qb, D, D, D, D, 0, (long long)D * D, (long long)B * S * D, 1.0f, 0);

    // Vt[b] = Wv @ Xb[b]^T : grid (16, 8, 4) = 512 blocks, MODE 0
    gemm8<unsigned short, 0><<<dim3(S / 128, D / 128, B), blk, 0, stream>>>(
        Wvb, Xb, Vt, D, D, S, D, 0, (long long)S * D, (long long)D * S, 1.0f, 0);

    // scores = (Q K^T)/32 : 136 tri-tiles/batch over 128 blocks/batch (8 spread extras)
    gemm8<float, 1><<<dim3(8, 16, B), blk, 0, stream>>>(
        Qb, Kb, Sc, D, D, S, D, (long long)S * D, (long long)S * D, (long long)S * S,
        0.03125f, 136);

    softmax_causal<<<B * S, 256, 0, stream>>>(Sc, P, S);

    // out = P @ Vt^T : 512 single-tile blocks, complementary row interleave, MODE 3
    gemm8<float, 3><<<dim3(8, 16, B), blk, 0, stream>>>(
        P, Vt, out, S, S, D, S, (long long)S * S, (long long)D * S, (long long)S * D,
        1.0f, 0);
}